// Round 10
// baseline (903.165 us; speedup 1.0000x reference)
//
#include <hip/hip_runtime.h>
#include <stdint.h>

#define B_    4
#define H_    16
#define S_    2048
#define D_    64
#define SCALE_LOG2E 0.1803368801111244f   // 0.125 * log2(e)

typedef __bf16 bf16x8 __attribute__((ext_vector_type(8)));
typedef __bf16 bf16x4 __attribute__((ext_vector_type(4)));
typedef float  f32x4  __attribute__((ext_vector_type(4)));

// ---- prep_k: K fp32 [bh][s][d] -> fragment-major bf16 image (proven).
// Slice (bh, e, sb) = 4KB, chunk C = ksub*128 + kd*64 + lhi*16 + l15 (16B each):
//   holds K[bh][e*64 + sb*32 + ksub*16 + l15][kd*32 + lhi*8 + 0..7]
__global__ __launch_bounds__(256)
void prep_k(const float* __restrict__ K, __bf16* __restrict__ img) {
    int t = blockIdx.x * 256 + threadIdx.x;
    int C = t & 255, slice = t >> 8;
    int sb = slice & 1, e = (slice >> 1) & 31, bh = slice >> 6;
    int l15 = C & 15, lhi = (C >> 4) & 3, kd = (C >> 6) & 1, ksub = C >> 7;
    const float* src = K + (((size_t)bh * S_ + e * 64 + sb * 32 + ksub * 16 + l15) * D_
                            + kd * 32 + lhi * 8);
    float4 a = *reinterpret_cast<const float4*>(src);
    float4 b = *reinterpret_cast<const float4*>(src + 4);
    bf16x8 w = { (__bf16)a.x,(__bf16)a.y,(__bf16)a.z,(__bf16)a.w,
                 (__bf16)b.x,(__bf16)b.y,(__bf16)b.z,(__bf16)b.w };
    *reinterpret_cast<bf16x8*>((char*)img + ((size_t)t << 4)) = w;
}

// ---- prep_v: V fp32 [bh][s][d] -> fragment-major transposed bf16 image (proven).
// Slice (bh, e, sb) = 4KB, chunk C2 = db*64 + lhi*16 + l15:
//   w[j] = V[bh][e*64 + sb*32 + lhi*4 + (j&3) + (j>>2)*16][db*16 + l15]
__global__ __launch_bounds__(256)
void prep_v(const float* __restrict__ V, __bf16* __restrict__ img) {
    __shared__ float Ls[64][65];
    const int tid = threadIdx.x;
    const int bh = blockIdx.x >> 5, e = blockIdx.x & 31;
    const float* Vp = V + ((size_t)bh * S_ + e * 64) * D_;
    for (int i = tid; i < 1024; i += 256) {
        int r = i >> 4, c = (i & 15) << 2;
        float4 v = reinterpret_cast<const float4*>(Vp)[i];
        Ls[r][c] = v.x; Ls[r][c+1] = v.y; Ls[r][c+2] = v.z; Ls[r][c+3] = v.w;
    }
    __syncthreads();
    char* base = (char*)img + (size_t)(bh * 32 + e) * 8192;
    #pragma unroll
    for (int m = tid; m < 512; m += 256) {
        int sb = m >> 8, C2 = m & 255;
        int db = C2 >> 6, lhi = (C2 >> 4) & 3, l15 = C2 & 15;
        bf16x8 w;
        #pragma unroll
        for (int j = 0; j < 8; ++j)
            w[j] = (__bf16)Ls[sb * 32 + lhi * 4 + (j & 3) + ((j >> 2) << 4)][db * 16 + l15];
        *reinterpret_cast<bf16x8*>(base + sb * 4096 + C2 * 16) = w;
    }
}

// ---------- main: 4 independent q16-waves per 256-thr block; no LDS, no barriers ----------
__global__ __launch_bounds__(256, 3)
void sdpa_main(const float* __restrict__ Q, const __bf16* __restrict__ Kimg,
               const __bf16* __restrict__ Vimg, const int* __restrict__ mask,
               float* __restrict__ ctx_out, float* __restrict__ attn_out)
{
    const int tid  = threadIdx.x;
    const int lane = tid & 63, wid = tid >> 6;
    const int l15  = lane & 15, lhi = lane >> 4;

    const int orig = blockIdx.x, cpx = gridDim.x >> 3;
    const int bid  = (orig & 7) * cpx + (orig >> 3);
    const int qt = bid & 31, bh = bid >> 5, b = bh >> 4;
    const int q16 = qt * 4 + wid;            // this wave's 16-row strip

    const char* kimgT = (const char*)Kimg + (size_t)bh * 262144;
    const char* vimgT = (const char*)Vimg + (size_t)bh * 262144;

    // Q fragment (B-operand), scale folded; q-col = l15, k-elems = kd*32 + lhi*8 + j
    bf16x8 bQ0, bQ1;
    {
        const float* qrow = Q + ((size_t)bh * S_ + q16 * 16 + l15) * D_ + lhi * 8;
        float4 a = *reinterpret_cast<const float4*>(qrow);
        float4 c = *reinterpret_cast<const float4*>(qrow + 4);
        bQ0 = (bf16x8){ (__bf16)(a.x*SCALE_LOG2E),(__bf16)(a.y*SCALE_LOG2E),
                        (__bf16)(a.z*SCALE_LOG2E),(__bf16)(a.w*SCALE_LOG2E),
                        (__bf16)(c.x*SCALE_LOG2E),(__bf16)(c.y*SCALE_LOG2E),
                        (__bf16)(c.z*SCALE_LOG2E),(__bf16)(c.w*SCALE_LOG2E) };
        a = *reinterpret_cast<const float4*>(qrow + 32);
        c = *reinterpret_cast<const float4*>(qrow + 36);
        bQ1 = (bf16x8){ (__bf16)(a.x*SCALE_LOG2E),(__bf16)(a.y*SCALE_LOG2E),
                        (__bf16)(a.z*SCALE_LOG2E),(__bf16)(a.w*SCALE_LOG2E),
                        (__bf16)(c.x*SCALE_LOG2E),(__bf16)(c.y*SCALE_LOG2E),
                        (__bf16)(c.z*SCALE_LOG2E),(__bf16)(c.w*SCALE_LOG2E) };
    }

    // mask words: 4 combos (sb,ksub) x 4 words of 8 tiles; bit (u*4 + r) set = masked
    uint32_t mA0,mA1,mA2,mA3, mB0,mB1,mB2,mB3, mC0,mC1,mC2,mC3, mD0,mD1,mD2,mD3;
    {
        const int* mb2 = mask + b * S_ + lhi * 4;
        auto packw = [&](int tw, uint32_t& a, uint32_t& bb, uint32_t& cc, uint32_t& dd) {
            a = bb = cc = dd = 0;
            #pragma unroll
            for (int u = 0; u < 8; ++u) {
                int e = (tw * 8 + u + qt) & 31;
                const int* p = mb2 + e * 64;
                int4 m0 = *reinterpret_cast<const int4*>(p);
                int4 m1 = *reinterpret_cast<const int4*>(p + 16);
                int4 m2 = *reinterpret_cast<const int4*>(p + 32);
                int4 m3 = *reinterpret_cast<const int4*>(p + 48);
                uint32_t nA = (m0.x?1u:0u)|(m0.y?2u:0u)|(m0.z?4u:0u)|(m0.w?8u:0u);
                uint32_t nB = (m1.x?1u:0u)|(m1.y?2u:0u)|(m1.z?4u:0u)|(m1.w?8u:0u);
                uint32_t nC = (m2.x?1u:0u)|(m2.y?2u:0u)|(m2.z?4u:0u)|(m2.w?8u:0u);
                uint32_t nD = (m3.x?1u:0u)|(m3.y?2u:0u)|(m3.z?4u:0u)|(m3.w?8u:0u);
                a |= nA << (u*4); bb |= nB << (u*4); cc |= nC << (u*4); dd |= nD << (u*4);
            }
        };
        packw(0, mA0, mB0, mC0, mD0);
        packw(1, mA1, mB1, mC1, mD1);
        packw(2, mA2, mB2, mC2, mD2);
        packw(3, mA3, mB3, mC3, mD3);
    }

    // K fragments kf[sb][ksub][kd]; self-overwriting single buffer (WAR handled in-order)
    bf16x8 kf[2][2][2];
    auto loadK = [&](int tt) {
        int e = (tt + qt) & 31;
        const char* p0 = kimgT + (size_t)(e * 2) * 4096 + lane * 16;
        kf[0][0][0] = *reinterpret_cast<const bf16x8*>(p0);
        kf[0][0][1] = *reinterpret_cast<const bf16x8*>(p0 + 1024);
        kf[0][1][0] = *reinterpret_cast<const bf16x8*>(p0 + 2048);
        kf[0][1][1] = *reinterpret_cast<const bf16x8*>(p0 + 3072);
        const char* p1 = p0 + 4096;
        kf[1][0][0] = *reinterpret_cast<const bf16x8*>(p1);
        kf[1][0][1] = *reinterpret_cast<const bf16x8*>(p1 + 1024);
        kf[1][1][0] = *reinterpret_cast<const bf16x8*>(p1 + 2048);
        kf[1][1][1] = *reinterpret_cast<const bf16x8*>(p1 + 3072);
    };
    // V fragments vv[sb][db]
    bf16x8 vv[2][4];
    auto loadV = [&](int tt) {
        int e = (tt + qt) & 31;
        const char* p0 = vimgT + (size_t)(e * 2) * 4096 + lane * 16;
        vv[0][0] = *reinterpret_cast<const bf16x8*>(p0);
        vv[0][1] = *reinterpret_cast<const bf16x8*>(p0 + 1024);
        vv[0][2] = *reinterpret_cast<const bf16x8*>(p0 + 2048);
        vv[0][3] = *reinterpret_cast<const bf16x8*>(p0 + 3072);
        const char* p1 = p0 + 4096;
        vv[1][0] = *reinterpret_cast<const bf16x8*>(p1);
        vv[1][1] = *reinterpret_cast<const bf16x8*>(p1 + 1024);
        vv[1][2] = *reinterpret_cast<const bf16x8*>(p1 + 2048);
        vv[1][3] = *reinterpret_cast<const bf16x8*>(p1 + 3072);
    };

    // ---------------- pass 1: row sums (wave-private) ----------------
    float ls = 0.f;
    loadK(0);
    auto sumExp = [&](const f32x4& acc, uint32_t nib) -> float {
        float p0 = (nib & 1u) ? 0.f : exp2f(acc[0]);
        float p1 = (nib & 2u) ? 0.f : exp2f(acc[1]);
        float p2 = (nib & 4u) ? 0.f : exp2f(acc[2]);
        float p3 = (nib & 8u) ? 0.f : exp2f(acc[3]);
        return (p0 + p1) + (p2 + p3);
    };
    auto pass1_8 = [&](int tw, uint32_t mA, uint32_t mB, uint32_t mC, uint32_t mD) {
        #pragma unroll 2
        for (int u = 0; u < 8; ++u) {
            int tt = tw * 8 + u;
            f32x4 z = {0.f,0.f,0.f,0.f};
            f32x4 a00 = __builtin_amdgcn_mfma_f32_16x16x32_bf16(kf[0][0][0], bQ0, z, 0,0,0);
            a00 = __builtin_amdgcn_mfma_f32_16x16x32_bf16(kf[0][0][1], bQ1, a00, 0,0,0);
            f32x4 a01 = __builtin_amdgcn_mfma_f32_16x16x32_bf16(kf[0][1][0], bQ0, z, 0,0,0);
            a01 = __builtin_amdgcn_mfma_f32_16x16x32_bf16(kf[0][1][1], bQ1, a01, 0,0,0);
            f32x4 a10 = __builtin_amdgcn_mfma_f32_16x16x32_bf16(kf[1][0][0], bQ0, z, 0,0,0);
            a10 = __builtin_amdgcn_mfma_f32_16x16x32_bf16(kf[1][0][1], bQ1, a10, 0,0,0);
            f32x4 a11 = __builtin_amdgcn_mfma_f32_16x16x32_bf16(kf[1][1][0], bQ0, z, 0,0,0);
            a11 = __builtin_amdgcn_mfma_f32_16x16x32_bf16(kf[1][1][1], bQ1, a11, 0,0,0);
            loadK((tt + 1) & 31);
            int sh = u * 4;
            ls += sumExp(a00, (mA >> sh) & 15u) + sumExp(a01, (mB >> sh) & 15u)
                + sumExp(a10, (mC >> sh) & 15u) + sumExp(a11, (mD >> sh) & 15u);
        }
    };
    pass1_8(0, mA0, mB0, mC0, mD0);
    pass1_8(1, mA1, mB1, mC1, mD1);
    pass1_8(2, mA2, mB2, mC2, mD2);
    pass1_8(3, mA3, mB3, mC3, mD3);

    ls += __shfl_xor(ls, 16);
    ls += __shfl_xor(ls, 32);
    const float rl = 1.0f / ls;

    // ---------------- pass 2: attn store (cached, 256B/row from one wave) + PV ----------------
    f32x4 ctx[4];
    #pragma unroll
    for (int db = 0; db < 4; ++db) ctx[db] = (f32x4){0.f,0.f,0.f,0.f};

    const size_t arow0 = (size_t)bh * S_ + (size_t)q16 * 16;
    float* arowp = attn_out + (arow0 + l15) * S_ + lhi * 4;

    loadK(0); loadV(0);
    auto pass2_8 = [&](int tw, uint32_t mA, uint32_t mB, uint32_t mC, uint32_t mD) {
        #pragma unroll 2
        for (int u = 0; u < 8; ++u) {
            int tt = tw * 8 + u;
            int e = (tt + qt) & 31;
            f32x4 z = {0.f,0.f,0.f,0.f};
            f32x4 a00 = __builtin_amdgcn_mfma_f32_16x16x32_bf16(kf[0][0][0], bQ0, z, 0,0,0);
            a00 = __builtin_amdgcn_mfma_f32_16x16x32_bf16(kf[0][0][1], bQ1, a00, 0,0,0);
            f32x4 a01 = __builtin_amdgcn_mfma_f32_16x16x32_bf16(kf[0][1][0], bQ0, z, 0,0,0);
            a01 = __builtin_amdgcn_mfma_f32_16x16x32_bf16(kf[0][1][1], bQ1, a01, 0,0,0);
            f32x4 a10 = __builtin_amdgcn_mfma_f32_16x16x32_bf16(kf[1][0][0], bQ0, z, 0,0,0);
            a10 = __builtin_amdgcn_mfma_f32_16x16x32_bf16(kf[1][0][1], bQ1, a10, 0,0,0);
            f32x4 a11 = __builtin_amdgcn_mfma_f32_16x16x32_bf16(kf[1][1][0], bQ0, z, 0,0,0);
            a11 = __builtin_amdgcn_mfma_f32_16x16x32_bf16(kf[1][1][1], bQ1, a11, 0,0,0);
            loadK((tt + 1) & 31);
            int sh = u * 4;
            uint32_t nA = (mA >> sh) & 15u, nB = (mB >> sh) & 15u;
            uint32_t nC = (mC >> sh) & 15u, nD = (mD >> sh) & 15u;
            f32x4 sA = { (nA&1u)?0.f:exp2f(a00[0])*rl, (nA&2u)?0.f:exp2f(a00[1])*rl,
                         (nA&4u)?0.f:exp2f(a00[2])*rl, (nA&8u)?0.f:exp2f(a00[3])*rl };
            f32x4 sB = { (nB&1u)?0.f:exp2f(a01[0])*rl, (nB&2u)?0.f:exp2f(a01[1])*rl,
                         (nB&4u)?0.f:exp2f(a01[2])*rl, (nB&8u)?0.f:exp2f(a01[3])*rl };
            f32x4 sC = { (nC&1u)?0.f:exp2f(a10[0])*rl, (nC&2u)?0.f:exp2f(a10[1])*rl,
                         (nC&4u)?0.f:exp2f(a10[2])*rl, (nC&8u)?0.f:exp2f(a10[3])*rl };
            f32x4 sD = { (nD&1u)?0.f:exp2f(a11[0])*rl, (nD&2u)?0.f:exp2f(a11[1])*rl,
                         (nD&4u)?0.f:exp2f(a11[2])*rl, (nD&8u)?0.f:exp2f(a11[3])*rl };
            float* ap = arowp + e * 64;
            *reinterpret_cast<f32x4*>(ap)      = sA;
            *reinterpret_cast<f32x4*>(ap + 16) = sB;
            *reinterpret_cast<f32x4*>(ap + 32) = sC;
            *reinterpret_cast<f32x4*>(ap + 48) = sD;
            bf16x8 Av0 = { (__bf16)sA[0],(__bf16)sA[1],(__bf16)sA[2],(__bf16)sA[3],
                           (__bf16)sB[0],(__bf16)sB[1],(__bf16)sB[2],(__bf16)sB[3] };
            bf16x8 Av1 = { (__bf16)sC[0],(__bf16)sC[1],(__bf16)sC[2],(__bf16)sC[3],
                           (__bf16)sD[0],(__bf16)sD[1],(__bf16)sD[2],(__bf16)sD[3] };
            #pragma unroll
            for (int db = 0; db < 4; ++db) {
                ctx[db] = __builtin_amdgcn_mfma_f32_16x16x32_bf16(Av0, vv[0][db], ctx[db], 0,0,0);
                ctx[db] = __builtin_amdgcn_mfma_f32_16x16x32_bf16(Av1, vv[1][db], ctx[db], 0,0,0);
            }
            loadV((tt + 1) & 31);
        }
    };
    pass2_8(0, mA0, mB0, mC0, mD0);
    pass2_8(1, mA1, mB1, mC1, mD1);
    pass2_8(2, mA2, mB2, mC2, mD2);
    pass2_8(3, mA3, mB3, mC3, mD3);

    // ---------------- ctx write: row = q16*16 + lhi*4 + r, col = db*16 + l15 ----------------
    #pragma unroll
    for (int db = 0; db < 4; ++db) {
        #pragma unroll
        for (int r = 0; r < 4; ++r) {
            ctx_out[(arow0 + lhi * 4 + r) * D_ + db * 16 + l15] = ctx[db][r];
        }
    }
}

extern "C" void kernel_launch(void* const* d_in, const int* in_sizes, int n_in,
                              void* d_out, int out_size, void* d_ws, size_t ws_size,
                              hipStream_t stream) {
    const float* Q    = (const float*)d_in[0];
    const float* K    = (const float*)d_in[1];
    const float* V    = (const float*)d_in[2];
    const int*   mask = (const int*)d_in[3];

    float* ctx_out  = (float*)d_out;
    float* attn_out = ctx_out + (size_t)B_ * H_ * S_ * D_;

    __bf16* Kimg = (__bf16*)d_ws;                              // 16.8 MB
    __bf16* Vimg = Kimg + (size_t)B_ * H_ * S_ * D_;           // 16.8 MB

    prep_k<<<4096, 256, 0, stream>>>(K, Kimg);
    prep_v<<<B_ * H_ * 32, 256, 0, stream>>>(V, Vimg);
    sdpa_main<<<B_ * H_ * 32, 256, 0, stream>>>(Q, Kimg, Vimg, mask, ctx_out, attn_out);
}

// Round 11
// 653.863 us; speedup vs baseline: 1.3813x; 1.3813x over previous
//
#include <hip/hip_runtime.h>
#include <stdint.h>

#define B_    4
#define H_    16
#define S_    2048
#define D_    64
#define SCALE_LOG2E 0.1803368801111244f   // 0.125 * log2(e)

typedef __bf16 bf16x8 __attribute__((ext_vector_type(8)));
typedef __bf16 bf16x4 __attribute__((ext_vector_type(4)));
typedef float  f32x4  __attribute__((ext_vector_type(4)));

// ---- prep_k: K fp32 [bh][s][d] -> fragment-major bf16 image (proven R8).
__global__ __launch_bounds__(256)
void prep_k(const float* __restrict__ K, __bf16* __restrict__ img) {
    int t = blockIdx.x * 256 + threadIdx.x;
    int C = t & 255, slice = t >> 8;
    int sb = slice & 1, e = (slice >> 1) & 31, bh = slice >> 6;
    int l15 = C & 15, lhi = (C >> 4) & 3, kd = (C >> 6) & 1, ksub = C >> 7;
    const float* src = K + (((size_t)bh * S_ + e * 64 + sb * 32 + ksub * 16 + l15) * D_
                            + kd * 32 + lhi * 8);
    float4 a = *reinterpret_cast<const float4*>(src);
    float4 b = *reinterpret_cast<const float4*>(src + 4);
    bf16x8 w = { (__bf16)a.x,(__bf16)a.y,(__bf16)a.z,(__bf16)a.w,
                 (__bf16)b.x,(__bf16)b.y,(__bf16)b.z,(__bf16)b.w };
    *reinterpret_cast<bf16x8*>((char*)img + ((size_t)t << 4)) = w;
}

// ---- prep_v: V fp32 [bh][s][d] -> fragment-major transposed bf16 image (proven R8).
__global__ __launch_bounds__(256)
void prep_v(const float* __restrict__ V, __bf16* __restrict__ img) {
    __shared__ float Ls[64][65];
    const int tid = threadIdx.x;
    const int bh = blockIdx.x >> 5, e = blockIdx.x & 31;
    const float* Vp = V + ((size_t)bh * S_ + e * 64) * D_;
    for (int i = tid; i < 1024; i += 256) {
        int r = i >> 4, c = (i & 15) << 2;
        float4 v = reinterpret_cast<const float4*>(Vp)[i];
        Ls[r][c] = v.x; Ls[r][c+1] = v.y; Ls[r][c+2] = v.z; Ls[r][c+3] = v.w;
    }
    __syncthreads();
    char* base = (char*)img + (size_t)(bh * 32 + e) * 8192;
    #pragma unroll
    for (int m = tid; m < 512; m += 256) {
        int sb = m >> 8, C2 = m & 255;
        int db = C2 >> 6, lhi = (C2 >> 4) & 3, l15 = C2 & 15;
        bf16x8 w;
        #pragma unroll
        for (int j = 0; j < 8; ++j)
            w[j] = (__bf16)Ls[sb * 32 + lhi * 4 + (j & 3) + ((j >> 2) << 4)][db * 16 + l15];
        *reinterpret_cast<bf16x8*>(base + sb * 4096 + C2 * 16) = w;
    }
}

// ---------- main: R8 structure + LDS-staged full-line attn stores ----------
__global__ __launch_bounds__(256, 2)
void sdpa_main(const float* __restrict__ Q, const __bf16* __restrict__ Kimg,
               const __bf16* __restrict__ Vimg, const int* __restrict__ mask,
               float* __restrict__ ctx_out, float* __restrict__ attn_out)
{
    __shared__ __align__(16) char smem[32768];   // Ps[2][64 rows][256B] / lsum / Cred

    const int tid  = threadIdx.x;
    const int lane = tid & 63, wid = tid >> 6;
    const int l15  = lane & 15, lhi = lane >> 4;
    const int par  = wid & 1;        // tile parity this wave owns
    const int sb   = wid >> 1;       // 32-wide k-slice within tile

    const int orig = blockIdx.x, cpx = gridDim.x >> 3;
    const int bid  = (orig & 7) * cpx + (orig >> 3);
    const int qt = bid & 31, bh = bid >> 5, b = bh >> 4;

    const char* kimgT = (const char*)Kimg + (size_t)bh * 262144;
    const char* vimgT = (const char*)Vimg + (size_t)bh * 262144;

    // Q fragments (B-operand), scale folded
    bf16x8 bQ[4][2];
    #pragma unroll
    for (int rb = 0; rb < 4; ++rb) {
        const float* qrow = Q + ((size_t)bh * S_ + qt * 64 + rb * 16 + l15) * D_ + lhi * 8;
        float4 a = *reinterpret_cast<const float4*>(qrow);
        float4 c = *reinterpret_cast<const float4*>(qrow + 4);
        bQ[rb][0] = (bf16x8){ (__bf16)(a.x*SCALE_LOG2E),(__bf16)(a.y*SCALE_LOG2E),
                              (__bf16)(a.z*SCALE_LOG2E),(__bf16)(a.w*SCALE_LOG2E),
                              (__bf16)(c.x*SCALE_LOG2E),(__bf16)(c.y*SCALE_LOG2E),
                              (__bf16)(c.z*SCALE_LOG2E),(__bf16)(c.w*SCALE_LOG2E) };
        a = *reinterpret_cast<const float4*>(qrow + 32);
        c = *reinterpret_cast<const float4*>(qrow + 36);
        bQ[rb][1] = (bf16x8){ (__bf16)(a.x*SCALE_LOG2E),(__bf16)(a.y*SCALE_LOG2E),
                              (__bf16)(a.z*SCALE_LOG2E),(__bf16)(a.w*SCALE_LOG2E),
                              (__bf16)(c.x*SCALE_LOG2E),(__bf16)(c.y*SCALE_LOG2E),
                              (__bf16)(c.z*SCALE_LOG2E),(__bf16)(c.w*SCALE_LOG2E) };
    }

    // mask bits: tile tt, ksub, r -> word tt>>2, bit (tt&3)*8 + ksub*4 + r (set = masked)
    uint32_t mwv[4] = {0, 0, 0, 0};
    {
        const int* mrow = mask + b * S_ + sb * 32 + lhi * 4;
        #pragma unroll
        for (int tt = 0; tt < 16; ++tt) {
            int e = (((tt + qt) & 15) << 1) | par;
            #pragma unroll
            for (int ksub = 0; ksub < 2; ++ksub) {
                int4 mm = *reinterpret_cast<const int4*>(mrow + e * 64 + ksub * 16);
                uint32_t nib = (mm.x ? 1u : 0u) | (mm.y ? 2u : 0u) |
                               (mm.z ? 4u : 0u) | (mm.w ? 8u : 0u);
                mwv[tt >> 2] |= nib << (((tt & 3) * 8) + ksub * 4);
            }
        }
    }

    // K fragments kf[buf][ksub][kd]
    bf16x8 kf[2][2][2];
    auto loadK = [&](int bufi, int tt) {
        int e = (((tt + qt) & 15) << 1) | par;
        const char* p = kimgT + (size_t)(e * 2 + sb) * 4096 + lane * 16;
        kf[bufi][0][0] = *reinterpret_cast<const bf16x8*>(p);
        kf[bufi][0][1] = *reinterpret_cast<const bf16x8*>(p + 1024);
        kf[bufi][1][0] = *reinterpret_cast<const bf16x8*>(p + 2048);
        kf[bufi][1][1] = *reinterpret_cast<const bf16x8*>(p + 3072);
    };
    // V fragments vv[buf][db]
    bf16x8 vv[2][4];
    auto loadV = [&](int bufi, int tt) {
        int e = (((tt + qt) & 15) << 1) | par;
        const char* p = vimgT + (size_t)(e * 2 + sb) * 4096 + lane * 16;
        vv[bufi][0] = *reinterpret_cast<const bf16x8*>(p);
        vv[bufi][1] = *reinterpret_cast<const bf16x8*>(p + 1024);
        vv[bufi][2] = *reinterpret_cast<const bf16x8*>(p + 2048);
        vv[bufi][3] = *reinterpret_cast<const bf16x8*>(p + 3072);
    };

    // ---------------- pass 1: row sums ----------------
    float ls[4] = {0.f, 0.f, 0.f, 0.f};
    loadK(0, 0);
    #pragma unroll
    for (int tt = 0; tt < 16; ++tt) {
        if (tt + 1 < 16) loadK((tt + 1) & 1, tt + 1);
        const int cur = tt & 1;
        #pragma unroll
        for (int ksub = 0; ksub < 2; ++ksub) {
            uint32_t nib = (mwv[tt >> 2] >> (((tt & 3) * 8) + ksub * 4)) & 15u;
            #pragma unroll
            for (int rb = 0; rb < 4; ++rb) {
                f32x4 acc = {0.f, 0.f, 0.f, 0.f};
                acc = __builtin_amdgcn_mfma_f32_16x16x32_bf16(kf[cur][ksub][0], bQ[rb][0], acc, 0, 0, 0);
                acc = __builtin_amdgcn_mfma_f32_16x16x32_bf16(kf[cur][ksub][1], bQ[rb][1], acc, 0, 0, 0);
                float p0 = (nib & 1u) ? 0.f : exp2f(acc[0]);
                float p1 = (nib & 2u) ? 0.f : exp2f(acc[1]);
                float p2 = (nib & 4u) ? 0.f : exp2f(acc[2]);
                float p3 = (nib & 8u) ? 0.f : exp2f(acc[3]);
                ls[rb] += (p0 + p1) + (p2 + p3);
            }
        }
    }

    // reduce lsum: over lhi (shfl), then across 4 waves (LDS)
    #pragma unroll
    for (int rb = 0; rb < 4; ++rb) {
        ls[rb] += __shfl_xor(ls[rb], 16);
        ls[rb] += __shfl_xor(ls[rb], 32);
    }
    float* lsb = reinterpret_cast<float*>(smem);
    if (lhi == 0) {
        #pragma unroll
        for (int rb = 0; rb < 4; ++rb) lsb[(wid * 4 + rb) * 16 + l15] = ls[rb];
    }
    __syncthreads();
    float rl[4];
    #pragma unroll
    for (int rb = 0; rb < 4; ++rb) {
        float tot = (lsb[rb * 16 + l15] + lsb[(4 + rb) * 16 + l15]) +
                    (lsb[(8 + rb) * 16 + l15] + lsb[(12 + rb) * 16 + l15]);
        rl[rb] = 1.0f / tot;
    }
    __syncthreads();   // lsb fully read before Ps overwrites smem

    // ---------------- pass 2: QK^T -> Ps (LDS) -> full-line attn stores + PV ----------------
    f32x4 ctx[4][4];
    #pragma unroll
    for (int rb = 0; rb < 4; ++rb)
        #pragma unroll
        for (int db = 0; db < 4; ++db) ctx[rb][db] = (f32x4){0.f,0.f,0.f,0.f};

    const size_t arowq = (size_t)bh * S_ + (size_t)qt * 64;
    char* psPar = smem + (par << 14);    // this parity's 16KB P-tile

    loadK(0, 0); loadV(0, 0);
    bf16x4 pk[2][4];
    #pragma unroll
    for (int tt = 0; tt < 16; ++tt) {
        if (tt + 1 < 16) { loadK((tt + 1) & 1, tt + 1); loadV((tt + 1) & 1, tt + 1); }
        const int cur = tt & 1;
        const int e = (((tt + qt) & 15) << 1) | par;
        // QK^T + exp + normalize -> LDS (swizzled 16B chunks) + pk registers
        #pragma unroll
        for (int rb = 0; rb < 4; ++rb) {
            const int q = rb * 16 + l15;
            #pragma unroll
            for (int ksub = 0; ksub < 2; ++ksub) {
                uint32_t nib = (mwv[tt >> 2] >> (((tt & 3) * 8) + ksub * 4)) & 15u;
                f32x4 acc = {0.f, 0.f, 0.f, 0.f};
                acc = __builtin_amdgcn_mfma_f32_16x16x32_bf16(kf[cur][ksub][0], bQ[rb][0], acc, 0, 0, 0);
                acc = __builtin_amdgcn_mfma_f32_16x16x32_bf16(kf[cur][ksub][1], bQ[rb][1], acc, 0, 0, 0);
                float p0 = (nib & 1u) ? 0.f : exp2f(acc[0]) * rl[rb];
                float p1 = (nib & 2u) ? 0.f : exp2f(acc[1]) * rl[rb];
                float p2 = (nib & 4u) ? 0.f : exp2f(acc[2]) * rl[rb];
                float p3 = (nib & 8u) ? 0.f : exp2f(acc[3]) * rl[rb];
                f32x4 st = { p0, p1, p2, p3 };
                int chunk = ((sb << 3) + (ksub << 2) + lhi) ^ (q & 15);
                *reinterpret_cast<f32x4*>(psPar + q * 256 + (chunk << 4)) = st;
                pk[ksub][rb] = (bf16x4){ (__bf16)p0, (__bf16)p1, (__bf16)p2, (__bf16)p3 };
            }
        }
        // PV from registers (independent of LDS)
        #pragma unroll
        for (int db = 0; db < 4; ++db) {
            #pragma unroll
            for (int rb = 0; rb < 4; ++rb) {
                bf16x8 Av;
                Av[0]=pk[0][rb][0]; Av[1]=pk[0][rb][1]; Av[2]=pk[0][rb][2]; Av[3]=pk[0][rb][3];
                Av[4]=pk[1][rb][0]; Av[5]=pk[1][rb][1]; Av[6]=pk[1][rb][2]; Av[7]=pk[1][rb][3];
                ctx[rb][db] = __builtin_amdgcn_mfma_f32_16x16x32_bf16(Av, vv[cur][db], ctx[rb][db], 0, 0, 0);
            }
        }
        __syncthreads();   // both sb-waves of this parity finished writing the P-tile
        // attn store: 4 rows x 256B contiguous per instruction (full 128B lines)
        #pragma unroll
        for (int it = 0; it < 8; ++it) {
            int row = sb * 32 + it * 4 + lhi;
            f32x4 v = *reinterpret_cast<f32x4*>(psPar + row * 256 + ((l15 ^ (row & 15)) << 4));
            *reinterpret_cast<f32x4*>(attn_out + (arowq + row) * S_ + e * 64 + l15 * 4) = v;
        }
        __syncthreads();   // WAR: stores done before next tile overwrites Ps
    }

    // ---------------- cross-wave ctx reduce ----------------
    __syncthreads();
    float* Cred = reinterpret_cast<float*>(smem);   // 64 x 65 floats
    for (int ph = 0; ph < 4; ++ph) {
        if (wid == ph) {
            #pragma unroll
            for (int rb = 0; rb < 4; ++rb)
                #pragma unroll
                for (int db = 0; db < 4; ++db)
                    #pragma unroll
                    for (int r = 0; r < 4; ++r) {
                        float* c = &Cred[(rb * 16 + lhi * 4 + r) * 65 + db * 16 + l15];
                        if (ph == 0) *c = ctx[rb][db][r];
                        else         *c += ctx[rb][db][r];
                    }
        }
        __syncthreads();
    }
    for (int i = tid; i < 4096; i += 256) {
        int q = i >> 6, d = i & 63;
        ctx_out[(arowq + q) * D_ + d] = Cred[q * 65 + d];
    }
}

extern "C" void kernel_launch(void* const* d_in, const int* in_sizes, int n_in,
                              void* d_out, int out_size, void* d_ws, size_t ws_size,
                              hipStream_t stream) {
    const float* Q    = (const float*)d_in[0];
    const float* K    = (const float*)d_in[1];
    const float* V    = (const float*)d_in[2];
    const int*   mask = (const int*)d_in[3];

    float* ctx_out  = (float*)d_out;
    float* attn_out = ctx_out + (size_t)B_ * H_ * S_ * D_;

    __bf16* Kimg = (__bf16*)d_ws;                              // 16.8 MB
    __bf16* Vimg = Kimg + (size_t)B_ * H_ * S_ * D_;           // 16.8 MB

    prep_k<<<4096, 256, 0, stream>>>(K, Kimg);
    prep_v<<<B_ * H_ * 32, 256, 0, stream>>>(V, Vimg);
    sdpa_main<<<B_ * H_ * 32, 256, 0, stream>>>(Q, Kimg, Vimg, mask, ctx_out, attn_out);
}